// Round 11
// baseline (261.321 us; speedup 1.0000x reference)
//
#include <hip/hip_runtime.h>
#include <math.h>

// B=8,T=2048,D=512,N=4096
static constexpr int D    = 512;
static constexpr int NPOS = 4096;
static constexpr int M    = 16384;
static constexpr float MIN_SCALE = 0.05f;

typedef unsigned short u16;
typedef __attribute__((ext_vector_type(8)))  short short8_t;   // bf16x8 MFMA frag (4 VGPR)
typedef __attribute__((ext_vector_type(16))) float f32x16_t;   // 32x32 MFMA acc
typedef __attribute__((ext_vector_type(8)))  unsigned short ushort8_t;

__device__ __forceinline__ u16 f2bf(float f) {
    unsigned u = __float_as_uint(f);
    unsigned r = (u + 0x7FFFu + ((u >> 16) & 1u)) >> 16;  // RN-even
    return (u16)r;
}
__device__ __forceinline__ float bf2f(u16 h) {
    return __uint_as_float(((unsigned)h) << 16);
}
__device__ __forceinline__ float exp2_hw(float z) {
    float r;
    asm("v_exp_f32 %0, %1" : "=v"(r) : "v"(z));   // full-range 2^x
    return r;
}
// packed bf16 convert: lo16 = bf16(a) RN-even, hi16 = bf16(b)
__device__ __forceinline__ unsigned cvt_pk_bf16(float a, float b) {
    unsigned r;
    asm("v_cvt_pk_bf16_f32 %0, %1, %2" : "=v"(r) : "v"(a), "v"(b));
    return r;
}
// spin until LDS counter >= tgt (all lanes read same addr -> broadcast)
__device__ __forceinline__ void lds_wait_ge(const volatile int* p, int tgt) {
    while (*p < tgt) __builtin_amdgcn_s_sleep(1);
}

// ---------------------------------------------------------------------------
// ws layout (floats unless noted):
//   [0)      pn   f32[4096]
//   [4096)   nit  f32[4096]       -log2e/((|t|+0.1)*scale)
//   byte 98304:   PB3 u16, frag-packed: idx ((ng*32+kg)*64+lane)*8
//                   n = ng*32+(lane&31), k = kg*16+(lane>>5)*8+c     (4 MB)
//   byte 4292608: VT3 u16, frag-packed: idx ((dg*256+kg)*64+lane)*8
//                   d = dg*32+(lane&31), n = kg*16+(lane>>5)*8+c     (4 MB)
// ---------------------------------------------------------------------------

// Fused precompute, roles by blockIdx.x (256 threads each):
//   [0,1024)      pn/nit        [1024,2048) PB3 pack
//   [2048,2560)   VT3 pack (LDS transpose)
__global__ __launch_bounds__(256) void pre_kernel(
    const float* __restrict__ x, const float* __restrict__ pos,
    const float* __restrict__ val, const float* __restrict__ temperature,
    const float* __restrict__ frozen_scale, const int* __restrict__ frozen,
    float* __restrict__ ws_f, u16* __restrict__ pb3, u16* __restrict__ vt3)
{
    const int b   = blockIdx.x;
    const int tid = threadIdx.x;

    if (b < 1024) {  // pn / nit
        const int wv = tid >> 6, lane = tid & 63;
        const int n  = b * 4 + wv;
        const float* row = pos + (size_t)n * D;
        float s = 0.f;
        #pragma unroll
        for (int q = 0; q < D; q += 64) { float v = row[q + lane]; s += v * v; }
        #pragma unroll
        for (int off = 32; off > 0; off >>= 1) s += __shfl_down(s, off, 64);
        if (lane == 0) {
            ws_f[n] = s;
            float es = (frozen[n] != 0) ? frozen_scale[n] : MIN_SCALE;
            float et = (fabsf(temperature[n]) + 0.1f) * es;
            ws_f[NPOS + n] = -1.442695040888963f / et;   // log2e folded in
        }
    } else if (b < 2048) {  // PB3 pack (frag index f is linear)
        const size_t f = (size_t)(b - 1024) * 256 + tid;
        const int lane = (int)(f & 63);
        const int kg   = (int)((f >> 6) & 31);
        const int ng   = (int)(f >> 11);
        const float* src = pos + ((size_t)(ng * 32 + (lane & 31)) * D
                                  + kg * 16 + (lane >> 5) * 8);
        const float4 a = *(const float4*)src;
        const float4 c = *(const float4*)(src + 4);
        ushort8_t v;
        v[0]=f2bf(a.x); v[1]=f2bf(a.y); v[2]=f2bf(a.z); v[3]=f2bf(a.w);
        v[4]=f2bf(c.x); v[5]=f2bf(c.y); v[6]=f2bf(c.z); v[7]=f2bf(c.w);
        *(ushort8_t*)(pb3 + f * 8) = v;
    } else {  // VT3 pack: 64n x 64d tile transpose via LDS
        __shared__ __attribute__((aligned(16))) float tile[64 * 68];
        const int b2 = b - 2048;
        const int n0 = (b2 & 63) * 64, d0 = (b2 >> 6) * 64;
        {
            const int row = tid >> 2, c0 = (tid & 3) * 16;
            const float* src = val + (size_t)(n0 + row) * D + d0 + c0;
            #pragma unroll
            for (int i = 0; i < 4; ++i)
                *(float4*)&tile[row * 68 + c0 + i * 4] = *(const float4*)(src + i * 4);
        }
        __syncthreads();
        #pragma unroll
        for (int ff = 0; ff < 2; ++ff) {
            const int f    = ff * 256 + tid;
            const int lane = f & 63;
            const int kgl  = (f >> 6) & 3;
            const int dgl  = (f >> 8) & 1;
            const int d_loc = dgl * 32 + (lane & 31);
            const int n_base = kgl * 16 + (lane >> 5) * 8;
            ushort8_t v;
            #pragma unroll
            for (int c = 0; c < 8; ++c) v[c] = f2bf(tile[(n_base + c) * 68 + d_loc]);
            const int dg = (d0 >> 5) + dgl;
            const int kga = (n0 >> 4) + kgl;
            *(ushort8_t*)(vt3 + ((size_t)(dg * 256 + kga) * 64 + lane) * 8) = v;
        }
    }
}

// ---------------------------------------------------------------------------
// Main kernel: 256 blocks x 1024 threads (16 waves), m-tile 64, 16 tiles of
// 256 n. Producer/consumer wave specialization, decoupled via LDS flags,
// producer credit-wait after GEMM1 (R10). SINGLE change vs R10: epilogue
// bf16 conversion via v_cvt_pk_bf16_f32 (1 inst / 2 elems, RN-even ==
// bit-identical to the manual f2bf) replacing 4-op f2bf + or/shift packing.
// Producer epilogue VALU is on the critical path (consumers spin on
// prod_cnt); ~224 cyc/tile/wave saved.
// ---------------------------------------------------------------------------
__global__ __launch_bounds__(1024, 4) void tidal_main(
    const float* __restrict__ ws_f, const u16* __restrict__ pb3,
    const u16* __restrict__ vt3, const float* __restrict__ x,
    float* __restrict__ out)
{
    __shared__ __attribute__((aligned(16))) u16 XBL[2][32][512];      // 64KB x-frags
    __shared__ __attribute__((aligned(16))) u16 WTF[2][2][16][512];   // 64KB w-frags, dbuf
    __shared__ float red[2][16][32];
    __shared__ float xnl[64];
    __shared__ float inv_s[64];
    __shared__ int   prod_cnt[16];
    __shared__ int   cons_cnt[16];

    const float* pn_arr = ws_f;
    const float* it_arr = ws_f + NPOS;

    const int tid  = threadIdx.x;
    const int lane = tid & 63;
    const int wave = tid >> 6;        // 0..15
    const int h    = lane >> 5;       // k-half within frag
    const int l31  = lane & 31;
    const int m0   = blockIdx.x * 64;

    if (tid < 16) { prod_cnt[tid] = 0; cons_cnt[tid] = 0; }

    // ---- stage x -> XBL (bf16 frag-packed) + xn partials ----
    {
        float xp = 0.f;
        #pragma unroll
        for (int s = 0; s < 4; ++s) {
            const int seg = wave * 4 + s;     // frag 0..63
            const int kgs = seg & 31;
            const int mhs = seg >> 5;         // == wave>>3 (const per wave)
            const float* src = x + (size_t)(m0 + mhs * 32 + l31) * D + kgs * 16 + h * 8;
            const float4 fa = *(const float4*)src;
            const float4 fc = *(const float4*)(src + 4);
            ushort8_t v;
            v[0]=f2bf(fa.x); v[1]=f2bf(fa.y); v[2]=f2bf(fa.z); v[3]=f2bf(fa.w);
            v[4]=f2bf(fc.x); v[5]=f2bf(fc.y); v[6]=f2bf(fc.z); v[7]=f2bf(fc.w);
            *(ushort8_t*)&XBL[mhs][kgs][lane * 8] = v;
            xp += fa.x*fa.x + fa.y*fa.y + fa.z*fa.z + fa.w*fa.w
                + fc.x*fc.x + fc.y*fc.y + fc.z*fc.z + fc.w*fc.w;
        }
        red[wave >> 3][(wave & 7) * 2 + h][l31] = xp;
    }
    __syncthreads();
    if (tid < 64) {
        float s = 0.f;
        #pragma unroll
        for (int j = 0; j < 16; ++j) s += red[tid >> 5][j][tid & 31];
        xnl[tid] = s;
    }
    __syncthreads();

    const bool is_prod = (wave < 8);
    const int  pq = wave;        // producer n-slice
    const int  cq = wave - 8;    // consumer d-slice (64 wide)

    float xn0 = 0.f, xn1 = 0.f;
    if (is_prod) { xn0 = xnl[l31]; xn1 = xnl[32 + l31]; }

    f32x16_t a0 = (f32x16_t)0.f, a1 = (f32x16_t)0.f;
    f32x16_t a2 = (f32x16_t)0.f, a3 = (f32x16_t)0.f;
    float den0 = 0.f, den1 = 0.f;

    const u16* vt_b0 = vt3 + (size_t)(2 * cq)     * 256 * 512 + lane * 8;
    const u16* vt_b1 = vt3 + (size_t)(2 * cq + 1) * 256 * 512 + lane * 8;

    if (is_prod) {
        for (int t = 0; t < 16; ++t) {
            // ---- GEMM1: S (32n x 64m) -- reads only PB3/XBL, runs ahead ----
            a0 = (f32x16_t)0.f; a1 = (f32x16_t)0.f;
            const u16* pbw = pb3 + (size_t)(t * 8 + pq) * (32 * 512) + lane * 8;
            #pragma unroll 4
            for (int kg = 0; kg < 32; ++kg) {
                const short8_t A  = *(const short8_t*)(pbw + (size_t)kg * 512);
                const short8_t B0 = *(const short8_t*)&XBL[0][kg][lane * 8];
                const short8_t B1 = *(const short8_t*)&XBL[1][kg][lane * 8];
                a0 = __builtin_amdgcn_mfma_f32_32x32x16_bf16(A, B0, a0, 0, 0, 0);
                a1 = __builtin_amdgcn_mfma_f32_32x32x16_bf16(A, B1, a1, 0, 0, 0);
            }

            // credit: WTF[t&1] free once consumers finished tile t-2
            // (only the epilogue WRITE needs this; GEMM1 ran during the wait)
            if (t >= 2) { lds_wait_ge(&cons_cnt[t - 2], 8); __threadfence_block(); }

            // ---- epilogue: w = 2^(dist*nit) -> WTF[t&1] (frag-packed) ----
            const int n0   = t * 256;
            const int bsel = t & 1;
            #pragma unroll
            for (int q = 0; q < 4; ++q) {
                const int nb = n0 + pq * 32 + 8 * q + 4 * h;
                const float4 pn4 = *(const float4*)(pn_arr + nb);
                const float4 it4 = *(const float4*)(it_arr + nb);
                const float pnv[4] = {pn4.x, pn4.y, pn4.z, pn4.w};
                const float itv[4] = {it4.x, it4.y, it4.z, it4.w};
                float w0[4], w1[4];
                #pragma unroll
                for (int r = 0; r < 4; ++r) {
                    const float d20 = xn0 + pnv[r] - 2.f * a0[4 * q + r];
                    w0[r] = exp2_hw(sqrtf(fmaxf(d20, 0.f)) * itv[r]);
                    const float d21 = xn1 + pnv[r] - 2.f * a1[4 * q + r];
                    w1[r] = exp2_hw(sqrtf(fmaxf(d21, 0.f)) * itv[r]);
                }
                // packed RN-even bf16 conversion (bit-identical to f2bf pairs)
                const unsigned p00 = cvt_pk_bf16(w0[0], w0[1]);
                const unsigned p01 = cvt_pk_bf16(w0[2], w0[3]);
                const unsigned p10 = cvt_pk_bf16(w1[0], w1[1]);
                const unsigned p11 = cvt_pk_bf16(w1[2], w1[3]);
                // den from the bf16-rounded values (same order as R10)
                den0 += __uint_as_float(p00 << 16);
                den0 += __uint_as_float(p00 & 0xffff0000u);
                den0 += __uint_as_float(p01 << 16);
                den0 += __uint_as_float(p01 & 0xffff0000u);
                den1 += __uint_as_float(p10 << 16);
                den1 += __uint_as_float(p10 & 0xffff0000u);
                den1 += __uint_as_float(p11 << 16);
                den1 += __uint_as_float(p11 & 0xffff0000u);

                const int kgp = pq * 2 + (q >> 1);
                const int gr  = (l31 + 32 * (q & 1)) * 8 + 4 * h;
                u16* dst0 = &WTF[bsel][0][kgp][gr];
                *(unsigned*)(dst0)     = p00;
                *(unsigned*)(dst0 + 2) = p01;
                u16* dst1 = &WTF[bsel][1][kgp][gr];
                *(unsigned*)(dst1)     = p10;
                *(unsigned*)(dst1 + 2) = p11;
            }
            __threadfence_block();                       // publish WTF writes
            if (lane == 0) atomicAdd(&prod_cnt[t], 1);   // signal
        }
    } else {
        for (int t = 0; t < 16; ++t) {
            lds_wait_ge(&prod_cnt[t], 8);                // tile t published
            __threadfence_block();                       // acquire
            const int bsel = t & 1;
            const u16* vb0 = vt_b0 + (size_t)(t * 16) * 512;
            const u16* vb1 = vt_b1 + (size_t)(t * 16) * 512;
            #pragma unroll 4
            for (int kg = 0; kg < 16; ++kg) {
                const short8_t A0 = *(const short8_t*)&WTF[bsel][0][kg][lane * 8];
                const short8_t A1 = *(const short8_t*)&WTF[bsel][1][kg][lane * 8];
                const short8_t B0 = *(const short8_t*)(vb0 + (size_t)kg * 512);
                const short8_t B1 = *(const short8_t*)(vb1 + (size_t)kg * 512);
                a0 = __builtin_amdgcn_mfma_f32_32x32x16_bf16(A0, B0, a0, 0, 0, 0);
                a1 = __builtin_amdgcn_mfma_f32_32x32x16_bf16(A0, B1, a1, 0, 0, 0);
                a2 = __builtin_amdgcn_mfma_f32_32x32x16_bf16(A1, B0, a2, 0, 0, 0);
                a3 = __builtin_amdgcn_mfma_f32_32x32x16_bf16(A1, B1, a3, 0, 0, 0);
            }
            __threadfence_block();                       // reads done
            if (lane == 0) atomicAdd(&cons_cnt[t], 1);   // release buffer
        }
    }
    __syncthreads();

    // ---------- den reduce + normalize + store ----------
    if (is_prod) {
        den0 += __shfl_xor(den0, 32, 64);
        den1 += __shfl_xor(den1, 32, 64);
        if (lane < 32) { red[0][pq][l31] = den0; red[1][pq][l31] = den1; }
    }
    __syncthreads();
    if (tid < 64) {
        float s = 0.f;
        #pragma unroll
        for (int j = 0; j < 8; ++j) s += red[tid >> 5][j][tid & 31];
        inv_s[tid] = 1.f / (s + 1e-8f);
    }
    __syncthreads();

    if (!is_prod) {
        #pragma unroll
        for (int q = 0; q < 4; ++q) {
            #pragma unroll
            for (int r = 0; r < 4; ++r) {
                const int mr = 8 * q + 4 * h + r;          // row within 32
                const float i0 = inv_s[mr];
                const float i1 = inv_s[32 + mr];
                float* o0 = out + (size_t)(m0 + mr) * D;
                float* o1 = out + (size_t)(m0 + 32 + mr) * D;
                o0[cq * 64 + l31]      = a0[4 * q + r] * i0;
                o0[cq * 64 + 32 + l31] = a1[4 * q + r] * i0;
                o1[cq * 64 + l31]      = a2[4 * q + r] * i1;
                o1[cq * 64 + 32 + l31] = a3[4 * q + r] * i1;
            }
        }
    }
}

extern "C" void kernel_launch(void* const* d_in, const int* in_sizes, int n_in,
                              void* d_out, int out_size, void* d_ws, size_t ws_size,
                              hipStream_t stream) {
    const float* xp  = (const float*)d_in[0];
    const float* pos = (const float*)d_in[1];
    const float* val = (const float*)d_in[2];
    const float* tmp = (const float*)d_in[3];
    const float* fsc = (const float*)d_in[4];
    const int*   frz = (const int*)d_in[5];
    float* outp = (float*)d_out;

    float* ws_f = (float*)d_ws;
    u16*   pb3  = (u16*)((char*)d_ws + 98304);
    u16*   vt3  = (u16*)((char*)d_ws + 4292608);

    pre_kernel<<<2560, 256, 0, stream>>>(xp, pos, val, tmp, fsc, frz,
                                         ws_f, pb3, vt3);
    tidal_main<<<M / 64, 1024, 0, stream>>>(ws_f, pb3, vt3, xp, outp);
}

// Round 12
// 228.399 us; speedup vs baseline: 1.1441x; 1.1441x over previous
//
#include <hip/hip_runtime.h>
#include <hip/hip_fp8.h>
#include <math.h>

// B=8,T=2048,D=512,N=4096
static constexpr int D    = 512;
static constexpr int NPOS = 4096;
static constexpr int M    = 16384;
static constexpr float MIN_SCALE = 0.05f;

typedef unsigned short u16;
typedef __attribute__((ext_vector_type(8)))  short short8_t;   // bf16x8 MFMA frag (4 VGPR)
typedef __attribute__((ext_vector_type(16))) float f32x16_t;   // 32x32 MFMA acc
typedef __attribute__((ext_vector_type(8)))  unsigned short ushort8_t;
typedef __attribute__((ext_vector_type(2)))  long long2_t;     // 2 fp8x8 frags (16B)

__device__ __forceinline__ u16 f2bf(float f) {
    unsigned u = __float_as_uint(f);
    unsigned r = (u + 0x7FFFu + ((u >> 16) & 1u)) >> 16;  // RN-even
    return (u16)r;
}
__device__ __forceinline__ float bf2f(u16 h) {
    return __uint_as_float(((unsigned)h) << 16);
}
__device__ __forceinline__ float exp2_hw(float z) {
    float r;
    asm("v_exp_f32 %0, %1" : "=v"(r) : "v"(z));   // full-range 2^x
    return r;
}
__device__ __forceinline__ unsigned char f2fp8(float f) {
    return __hip_fp8_e4m3(f).__x;                 // OCP e4m3, RNE+sat
}
// spin until LDS counter >= tgt (all lanes read same addr -> broadcast)
__device__ __forceinline__ void lds_wait_ge(const volatile int* p, int tgt) {
    while (*p < tgt) __builtin_amdgcn_s_sleep(1);
}

// ---------------------------------------------------------------------------
// ws layout:
//   [0)      pn   f32[4096]
//   [4096)   nit  f32[4096]       -log2e/((|t|+0.1)*scale)
//   byte 98304:   PB8 fp8-e4m3, PAIR-packed: idx ((ng*16+kgp)*64+lane)*16
//                   n = ng*32+(lane&31); bytes 0..7 = kg=2*kgp,
//                   bytes 8..15 = kg=2*kgp+1; k = kg*16+(lane>>5)*8+c   (2 MB)
//   byte 4292608: VT3 u16 bf16, frag-packed: idx ((dg*256+kg)*64+lane)*8
//                   d = dg*32+(lane&31), n = kg*16+(lane>>5)*8+c        (4 MB)
// ---------------------------------------------------------------------------

// Fused precompute, roles by blockIdx.x (256 threads each):
//   [0,1024) pn/nit   [1024,1536) PB8 fp8 pack   [1536,2048) VT3 pack
__global__ __launch_bounds__(256) void pre_kernel(
    const float* __restrict__ x, const float* __restrict__ pos,
    const float* __restrict__ val, const float* __restrict__ temperature,
    const float* __restrict__ frozen_scale, const int* __restrict__ frozen,
    float* __restrict__ ws_f, unsigned char* __restrict__ pb8,
    u16* __restrict__ vt3)
{
    const int b   = blockIdx.x;
    const int tid = threadIdx.x;

    if (b < 1024) {  // pn / nit
        const int wv = tid >> 6, lane = tid & 63;
        const int n  = b * 4 + wv;
        const float* row = pos + (size_t)n * D;
        float s = 0.f;
        #pragma unroll
        for (int q = 0; q < D; q += 64) { float v = row[q + lane]; s += v * v; }
        #pragma unroll
        for (int off = 32; off > 0; off >>= 1) s += __shfl_down(s, off, 64);
        if (lane == 0) {
            ws_f[n] = s;
            float es = (frozen[n] != 0) ? frozen_scale[n] : MIN_SCALE;
            float et = (fabsf(temperature[n]) + 0.1f) * es;
            ws_f[NPOS + n] = -1.442695040888963f / et;   // log2e folded in
        }
    } else if (b < 1536) {  // PB8 fp8 pair-pack (131072 items, 1/thread)
        const size_t f = (size_t)(b - 1024) * 256 + tid;
        const int lane = (int)(f & 63);
        const int kgp  = (int)((f >> 6) & 15);
        const int ng   = (int)(f >> 10);
        const float* s0 = pos + ((size_t)(ng * 32 + (lane & 31)) * D
                                 + kgp * 32 + (lane >> 5) * 8);
        const float4 a = *(const float4*)s0;
        const float4 c = *(const float4*)(s0 + 4);
        const float4 e = *(const float4*)(s0 + 16);
        const float4 g = *(const float4*)(s0 + 20);
        union { unsigned char bb[16]; uint4 u; } pk;
        pk.bb[0]=f2fp8(a.x);  pk.bb[1]=f2fp8(a.y);  pk.bb[2]=f2fp8(a.z);  pk.bb[3]=f2fp8(a.w);
        pk.bb[4]=f2fp8(c.x);  pk.bb[5]=f2fp8(c.y);  pk.bb[6]=f2fp8(c.z);  pk.bb[7]=f2fp8(c.w);
        pk.bb[8]=f2fp8(e.x);  pk.bb[9]=f2fp8(e.y);  pk.bb[10]=f2fp8(e.z); pk.bb[11]=f2fp8(e.w);
        pk.bb[12]=f2fp8(g.x); pk.bb[13]=f2fp8(g.y); pk.bb[14]=f2fp8(g.z); pk.bb[15]=f2fp8(g.w);
        *(uint4*)(pb8 + f * 16) = pk.u;
    } else {  // VT3 pack: 64n x 64d tile transpose via LDS (bf16, unchanged)
        __shared__ __attribute__((aligned(16))) float tile[64 * 68];
        const int b2 = b - 1536;
        const int n0 = (b2 & 63) * 64, d0 = (b2 >> 6) * 64;
        {
            const int row = tid >> 2, c0 = (tid & 3) * 16;
            const float* src = val + (size_t)(n0 + row) * D + d0 + c0;
            #pragma unroll
            for (int i = 0; i < 4; ++i)
                *(float4*)&tile[row * 68 + c0 + i * 4] = *(const float4*)(src + i * 4);
        }
        __syncthreads();
        #pragma unroll
        for (int ff = 0; ff < 2; ++ff) {
            const int f    = ff * 256 + tid;
            const int lane = f & 63;
            const int kgl  = (f >> 6) & 3;
            const int dgl  = (f >> 8) & 1;
            const int d_loc = dgl * 32 + (lane & 31);
            const int n_base = kgl * 16 + (lane >> 5) * 8;
            ushort8_t v;
            #pragma unroll
            for (int c = 0; c < 8; ++c) v[c] = f2bf(tile[(n_base + c) * 68 + d_loc]);
            const int dg = (d0 >> 5) + dgl;
            const int kga = (n0 >> 4) + kgl;
            *(ushort8_t*)(vt3 + ((size_t)(dg * 256 + kga) * 64 + lane) * 8) = v;
        }
    }
}

// ---------------------------------------------------------------------------
// Main kernel: 256 blocks x 1024 threads (16 waves), m-tile 64, 16 tiles of
// 256 n. R10 structure (flag-decoupled producer/consumer, credit-wait after
// GEMM1). SINGLE change vs R10: GEMM1 operands in fp8 e4m3, pair-packed --
// A-loads 32->16 b128 requests/tile, LDS reads 64->32, chip L2 stream
// 2.0 -> 1.5 GB. W/V/GEMM2/epilogue stay bf16/f32 (unchanged math).
// ---------------------------------------------------------------------------
__global__ __launch_bounds__(1024, 4) void tidal_main(
    const float* __restrict__ ws_f, const unsigned char* __restrict__ pb8,
    const u16* __restrict__ vt3, const float* __restrict__ x,
    float* __restrict__ out)
{
    __shared__ __attribute__((aligned(16))) unsigned char XBL8[2][16][64][16]; // 32KB x fp8
    __shared__ __attribute__((aligned(16))) u16 WTF[2][2][16][512];   // 64KB w-frags, dbuf
    __shared__ float red[2][16][32];
    __shared__ float xnl[64];
    __shared__ float inv_s[64];
    __shared__ int   prod_cnt[16];
    __shared__ int   cons_cnt[16];

    const float* pn_arr = ws_f;
    const float* it_arr = ws_f + NPOS;

    const int tid  = threadIdx.x;
    const int lane = tid & 63;
    const int wave = tid >> 6;        // 0..15
    const int h    = lane >> 5;       // k-half within frag
    const int l31  = lane & 31;
    const int m0   = blockIdx.x * 64;

    if (tid < 16) { prod_cnt[tid] = 0; cons_cnt[tid] = 0; }

    // ---- stage x -> XBL8 (fp8 pair-packed) + xn partials (f32 exact) ----
    {
        float xp = 0.f;
        #pragma unroll
        for (int s = 0; s < 2; ++s) {
            const int row = wave * 2 + s;     // 0..31
            const int mhs = row >> 4;         // const per wave
            const int kgp = row & 15;
            const float* src = x + (size_t)(m0 + mhs * 32 + l31) * D
                               + kgp * 32 + h * 8;
            const float4 a = *(const float4*)src;
            const float4 c = *(const float4*)(src + 4);
            const float4 e = *(const float4*)(src + 16);
            const float4 g = *(const float4*)(src + 20);
            union { unsigned char bb[16]; uint4 u; } pk;
            pk.bb[0]=f2fp8(a.x);  pk.bb[1]=f2fp8(a.y);  pk.bb[2]=f2fp8(a.z);  pk.bb[3]=f2fp8(a.w);
            pk.bb[4]=f2fp8(c.x);  pk.bb[5]=f2fp8(c.y);  pk.bb[6]=f2fp8(c.z);  pk.bb[7]=f2fp8(c.w);
            pk.bb[8]=f2fp8(e.x);  pk.bb[9]=f2fp8(e.y);  pk.bb[10]=f2fp8(e.z); pk.bb[11]=f2fp8(e.w);
            pk.bb[12]=f2fp8(g.x); pk.bb[13]=f2fp8(g.y); pk.bb[14]=f2fp8(g.z); pk.bb[15]=f2fp8(g.w);
            *(uint4*)&XBL8[mhs][kgp][lane][0] = pk.u;
            xp += a.x*a.x + a.y*a.y + a.z*a.z + a.w*a.w
                + c.x*c.x + c.y*c.y + c.z*c.z + c.w*c.w
                + e.x*e.x + e.y*e.y + e.z*e.z + e.w*e.w
                + g.x*g.x + g.y*g.y + g.z*g.z + g.w*g.w;
        }
        xp += __shfl_xor(xp, 32, 64);
        if (lane < 32) red[wave >> 3][wave & 7][l31] = xp;
    }
    __syncthreads();
    if (tid < 64) {
        float s = 0.f;
        #pragma unroll
        for (int j = 0; j < 8; ++j) s += red[tid >> 5][j][tid & 31];
        xnl[tid] = s;
    }
    __syncthreads();

    const bool is_prod = (wave < 8);
    const int  pq = wave;        // producer n-slice
    const int  cq = wave - 8;    // consumer d-slice (64 wide)

    float xn0 = 0.f, xn1 = 0.f;
    if (is_prod) { xn0 = xnl[l31]; xn1 = xnl[32 + l31]; }

    f32x16_t a0 = (f32x16_t)0.f, a1 = (f32x16_t)0.f;
    f32x16_t a2 = (f32x16_t)0.f, a3 = (f32x16_t)0.f;
    float den0 = 0.f, den1 = 0.f;

    const u16* vt_b0 = vt3 + (size_t)(2 * cq)     * 256 * 512 + lane * 8;
    const u16* vt_b1 = vt3 + (size_t)(2 * cq + 1) * 256 * 512 + lane * 8;

    if (is_prod) {
        for (int t = 0; t < 16; ++t) {
            // ---- GEMM1 (fp8): S (32n x 64m), 16 b128 A-loads/tile ----
            a0 = (f32x16_t)0.f; a1 = (f32x16_t)0.f;
            const unsigned char* pbw = pb8
                + (size_t)(t * 8 + pq) * (16 * 1024) + lane * 16;
            #pragma unroll 4
            for (int kgp = 0; kgp < 16; ++kgp) {
                const long2_t A  = *(const long2_t*)(pbw + (size_t)kgp * 1024);
                const long2_t B0 = *(const long2_t*)&XBL8[0][kgp][lane][0];
                const long2_t B1 = *(const long2_t*)&XBL8[1][kgp][lane][0];
                a0 = __builtin_amdgcn_mfma_f32_32x32x16_fp8_fp8(A[0], B0[0], a0, 0, 0, 0);
                a1 = __builtin_amdgcn_mfma_f32_32x32x16_fp8_fp8(A[0], B1[0], a1, 0, 0, 0);
                a0 = __builtin_amdgcn_mfma_f32_32x32x16_fp8_fp8(A[1], B0[1], a0, 0, 0, 0);
                a1 = __builtin_amdgcn_mfma_f32_32x32x16_fp8_fp8(A[1], B1[1], a1, 0, 0, 0);
            }

            // credit: WTF[t&1] free once consumers finished tile t-2
            if (t >= 2) { lds_wait_ge(&cons_cnt[t - 2], 8); __threadfence_block(); }

            // ---- epilogue: w = 2^(dist*nit) -> WTF[t&1] (R10 exact) ----
            const int n0   = t * 256;
            const int bsel = t & 1;
            #pragma unroll
            for (int q = 0; q < 4; ++q) {
                const int nb = n0 + pq * 32 + 8 * q + 4 * h;
                const float4 pn4 = *(const float4*)(pn_arr + nb);
                const float4 it4 = *(const float4*)(it_arr + nb);
                const float pnv[4] = {pn4.x, pn4.y, pn4.z, pn4.w};
                const float itv[4] = {it4.x, it4.y, it4.z, it4.w};
                u16 h0[4], h1[4];
                #pragma unroll
                for (int r = 0; r < 4; ++r) {
                    const float d20 = xn0 + pnv[r] - 2.f * a0[4 * q + r];
                    const float w0  = exp2_hw(sqrtf(fmaxf(d20, 0.f)) * itv[r]);
                    h0[r] = f2bf(w0); den0 += bf2f(h0[r]);
                    const float d21 = xn1 + pnv[r] - 2.f * a1[4 * q + r];
                    const float w1  = exp2_hw(sqrtf(fmaxf(d21, 0.f)) * itv[r]);
                    h1[r] = f2bf(w1); den1 += bf2f(h1[r]);
                }
                const int kgp = pq * 2 + (q >> 1);
                const int gr  = (l31 + 32 * (q & 1)) * 8 + 4 * h;
                u16* dst0 = &WTF[bsel][0][kgp][gr];
                *(unsigned*)(dst0)     = (unsigned)h0[0] | ((unsigned)h0[1] << 16);
                *(unsigned*)(dst0 + 2) = (unsigned)h0[2] | ((unsigned)h0[3] << 16);
                u16* dst1 = &WTF[bsel][1][kgp][gr];
                *(unsigned*)(dst1)     = (unsigned)h1[0] | ((unsigned)h1[1] << 16);
                *(unsigned*)(dst1 + 2) = (unsigned)h1[2] | ((unsigned)h1[3] << 16);
            }
            __threadfence_block();                       // publish WTF writes
            if (lane == 0) atomicAdd(&prod_cnt[t], 1);   // signal
        }
    } else {
        for (int t = 0; t < 16; ++t) {
            lds_wait_ge(&prod_cnt[t], 8);                // tile t published
            __threadfence_block();                       // acquire
            const int bsel = t & 1;
            const u16* vb0 = vt_b0 + (size_t)(t * 16) * 512;
            const u16* vb1 = vt_b1 + (size_t)(t * 16) * 512;
            #pragma unroll 4
            for (int kg = 0; kg < 16; ++kg) {
                const short8_t A0 = *(const short8_t*)&WTF[bsel][0][kg][lane * 8];
                const short8_t A1 = *(const short8_t*)&WTF[bsel][1][kg][lane * 8];
                const short8_t B0 = *(const short8_t*)(vb0 + (size_t)kg * 512);
                const short8_t B1 = *(const short8_t*)(vb1 + (size_t)kg * 512);
                a0 = __builtin_amdgcn_mfma_f32_32x32x16_bf16(A0, B0, a0, 0, 0, 0);
                a1 = __builtin_amdgcn_mfma_f32_32x32x16_bf16(A0, B1, a1, 0, 0, 0);
                a2 = __builtin_amdgcn_mfma_f32_32x32x16_bf16(A1, B0, a2, 0, 0, 0);
                a3 = __builtin_amdgcn_mfma_f32_32x32x16_bf16(A1, B1, a3, 0, 0, 0);
            }
            __threadfence_block();                       // reads done
            if (lane == 0) atomicAdd(&cons_cnt[t], 1);   // release buffer
        }
    }
    __syncthreads();

    // ---------- den reduce + normalize + store ----------
    if (is_prod) {
        den0 += __shfl_xor(den0, 32, 64);
        den1 += __shfl_xor(den1, 32, 64);
        if (lane < 32) { red[0][pq][l31] = den0; red[1][pq][l31] = den1; }
    }
    __syncthreads();
    if (tid < 64) {
        float s = 0.f;
        #pragma unroll
        for (int j = 0; j < 8; ++j) s += red[tid >> 5][j][tid & 31];
        inv_s[tid] = 1.f / (s + 1e-8f);
    }
    __syncthreads();

    if (!is_prod) {
        #pragma unroll
        for (int q = 0; q < 4; ++q) {
            #pragma unroll
            for (int r = 0; r < 4; ++r) {
                const int mr = 8 * q + 4 * h + r;          // row within 32
                const float i0 = inv_s[mr];
                const float i1 = inv_s[32 + mr];
                float* o0 = out + (size_t)(m0 + mr) * D;
                float* o1 = out + (size_t)(m0 + 32 + mr) * D;
                o0[cq * 64 + l31]      = a0[4 * q + r] * i0;
                o0[cq * 64 + 32 + l31] = a1[4 * q + r] * i0;
                o1[cq * 64 + l31]      = a2[4 * q + r] * i1;
                o1[cq * 64 + 32 + l31] = a3[4 * q + r] * i1;
            }
        }
    }
}

extern "C" void kernel_launch(void* const* d_in, const int* in_sizes, int n_in,
                              void* d_out, int out_size, void* d_ws, size_t ws_size,
                              hipStream_t stream) {
    const float* xp  = (const float*)d_in[0];
    const float* pos = (const float*)d_in[1];
    const float* val = (const float*)d_in[2];
    const float* tmp = (const float*)d_in[3];
    const float* fsc = (const float*)d_in[4];
    const int*   frz = (const int*)d_in[5];
    float* outp = (float*)d_out;

    float*         ws_f = (float*)d_ws;
    unsigned char* pb8  = (unsigned char*)d_ws + 98304;
    u16*           vt3  = (u16*)((char*)d_ws + 4292608);

    pre_kernel<<<2048, 256, 0, stream>>>(xp, pos, val, tmp, fsc, frz,
                                         ws_f, pb8, vt3);
    tidal_main<<<M / 64, 1024, 0, stream>>>(ws_f, pb8, vt3, xp, outp);
}

// Round 13
// 226.994 us; speedup vs baseline: 1.1512x; 1.0062x over previous
//
#include <hip/hip_runtime.h>
#include <hip/hip_fp8.h>
#include <math.h>

// B=8,T=2048,D=512,N=4096
static constexpr int D    = 512;
static constexpr int NPOS = 4096;
static constexpr int M    = 16384;
static constexpr float MIN_SCALE = 0.05f;

typedef unsigned short u16;
typedef __attribute__((ext_vector_type(8)))  short short8_t;   // bf16x8 MFMA frag (4 VGPR)
typedef __attribute__((ext_vector_type(16))) float f32x16_t;   // 32x32 MFMA acc
typedef __attribute__((ext_vector_type(8)))  unsigned short ushort8_t;
typedef __attribute__((ext_vector_type(2)))  long long2_t;     // 2 fp8x8 frags (16B)

__device__ __forceinline__ u16 f2bf(float f) {
    unsigned u = __float_as_uint(f);
    unsigned r = (u + 0x7FFFu + ((u >> 16) & 1u)) >> 16;  // RN-even
    return (u16)r;
}
__device__ __forceinline__ float bf2f(u16 h) {
    return __uint_as_float(((unsigned)h) << 16);
}
__device__ __forceinline__ float exp2_hw(float z) {
    float r;
    asm("v_exp_f32 %0, %1" : "=v"(r) : "v"(z));   // full-range 2^x
    return r;
}
__device__ __forceinline__ unsigned char f2fp8(float f) {
    return __hip_fp8_e4m3(f).__x;                 // OCP e4m3, RNE+sat
}
// spin until LDS counter >= tgt (all lanes read same addr -> broadcast)
__device__ __forceinline__ void lds_wait_ge(const volatile int* p, int tgt) {
    while (*p < tgt) __builtin_amdgcn_s_sleep(1);
}

// ---------------------------------------------------------------------------
// ws layout:
//   [0)      pn   f32[4096]
//   [4096)   nit  f32[4096]       -log2e/((|t|+0.1)*scale)
//   byte 98304:   PB8 fp8-e4m3, PAIR-packed: idx ((ng*16+kgp)*64+lane)*16
//                   n = ng*32+(lane&31); bytes 0..7 = kg=2*kgp,
//                   bytes 8..15 = kg=2*kgp+1; k = kg*16+(lane>>5)*8+c   (2 MB)
//   byte 4292608: VT3 u16 bf16, frag-packed: idx ((dg*256+kg)*64+lane)*8
//                   d = dg*32+(lane&31), n = kg*16+(lane>>5)*8+c        (4 MB)
// ---------------------------------------------------------------------------

// Fused precompute, roles by blockIdx.x (256 threads each):
//   [0,1024) pn/nit   [1024,1536) PB8 fp8 pack   [1536,2048) VT3 pack
__global__ __launch_bounds__(256) void pre_kernel(
    const float* __restrict__ x, const float* __restrict__ pos,
    const float* __restrict__ val, const float* __restrict__ temperature,
    const float* __restrict__ frozen_scale, const int* __restrict__ frozen,
    float* __restrict__ ws_f, unsigned char* __restrict__ pb8,
    u16* __restrict__ vt3)
{
    const int b   = blockIdx.x;
    const int tid = threadIdx.x;

    if (b < 1024) {  // pn / nit
        const int wv = tid >> 6, lane = tid & 63;
        const int n  = b * 4 + wv;
        const float* row = pos + (size_t)n * D;
        float s = 0.f;
        #pragma unroll
        for (int q = 0; q < D; q += 64) { float v = row[q + lane]; s += v * v; }
        #pragma unroll
        for (int off = 32; off > 0; off >>= 1) s += __shfl_down(s, off, 64);
        if (lane == 0) {
            ws_f[n] = s;
            float es = (frozen[n] != 0) ? frozen_scale[n] : MIN_SCALE;
            float et = (fabsf(temperature[n]) + 0.1f) * es;
            ws_f[NPOS + n] = -1.442695040888963f / et;   // log2e folded in
        }
    } else if (b < 1536) {  // PB8 fp8 pair-pack (131072 items, 1/thread)
        const size_t f = (size_t)(b - 1024) * 256 + tid;
        const int lane = (int)(f & 63);
        const int kgp  = (int)((f >> 6) & 15);
        const int ng   = (int)(f >> 10);
        const float* s0 = pos + ((size_t)(ng * 32 + (lane & 31)) * D
                                 + kgp * 32 + (lane >> 5) * 8);
        const float4 a = *(const float4*)s0;
        const float4 c = *(const float4*)(s0 + 4);
        const float4 e = *(const float4*)(s0 + 16);
        const float4 g = *(const float4*)(s0 + 20);
        union { unsigned char bb[16]; uint4 u; } pk;
        pk.bb[0]=f2fp8(a.x);  pk.bb[1]=f2fp8(a.y);  pk.bb[2]=f2fp8(a.z);  pk.bb[3]=f2fp8(a.w);
        pk.bb[4]=f2fp8(c.x);  pk.bb[5]=f2fp8(c.y);  pk.bb[6]=f2fp8(c.z);  pk.bb[7]=f2fp8(c.w);
        pk.bb[8]=f2fp8(e.x);  pk.bb[9]=f2fp8(e.y);  pk.bb[10]=f2fp8(e.z); pk.bb[11]=f2fp8(e.w);
        pk.bb[12]=f2fp8(g.x); pk.bb[13]=f2fp8(g.y); pk.bb[14]=f2fp8(g.z); pk.bb[15]=f2fp8(g.w);
        *(uint4*)(pb8 + f * 16) = pk.u;
    } else {  // VT3 pack: 64n x 64d tile transpose via LDS (bf16, unchanged)
        __shared__ __attribute__((aligned(16))) float tile[64 * 68];
        const int b2 = b - 1536;
        const int n0 = (b2 & 63) * 64, d0 = (b2 >> 6) * 64;
        {
            const int row = tid >> 2, c0 = (tid & 3) * 16;
            const float* src = val + (size_t)(n0 + row) * D + d0 + c0;
            #pragma unroll
            for (int i = 0; i < 4; ++i)
                *(float4*)&tile[row * 68 + c0 + i * 4] = *(const float4*)(src + i * 4);
        }
        __syncthreads();
        #pragma unroll
        for (int ff = 0; ff < 2; ++ff) {
            const int f    = ff * 256 + tid;
            const int lane = f & 63;
            const int kgl  = (f >> 6) & 3;
            const int dgl  = (f >> 8) & 1;
            const int d_loc = dgl * 32 + (lane & 31);
            const int n_base = kgl * 16 + (lane >> 5) * 8;
            ushort8_t v;
            #pragma unroll
            for (int c = 0; c < 8; ++c) v[c] = f2bf(tile[(n_base + c) * 68 + d_loc]);
            const int dg = (d0 >> 5) + dgl;
            const int kga = (n0 >> 4) + kgl;
            *(ushort8_t*)(vt3 + ((size_t)(dg * 256 + kga) * 64 + lane) * 8) = v;
        }
    }
}

// ---------------------------------------------------------------------------
// Main kernel: 256 blocks x 1024 threads (16 waves), m-tile 64, 16 tiles of
// 256 n. R12 structure (fp8 GEMM1, flag-decoupled producer/consumer,
// credit-wait after GEMM1). Changes vs R12:
//   (1) WTF TRIPLE-buffered (96KB, fits since XBL8 is 32KB) -> producer
//       credit deepens to cons_cnt[t-3]: 2 tiles of run-ahead absorb the
//       producer/consumer rate mismatch, keeping both L2 streams in flight.
//   (2) Consumers prefetch the first 2 kg of VT3 (flag-independent) BEFORE
//       the prod_cnt spin -> V latency hides under the producer epilogue.
// ---------------------------------------------------------------------------
__global__ __launch_bounds__(1024, 4) void tidal_main(
    const float* __restrict__ ws_f, const unsigned char* __restrict__ pb8,
    const u16* __restrict__ vt3, const float* __restrict__ x,
    float* __restrict__ out)
{
    __shared__ __attribute__((aligned(16))) unsigned char XBL8[2][16][64][16]; // 32KB x fp8
    __shared__ __attribute__((aligned(16))) u16 WTF[3][2][16][512];   // 96KB w-frags, 3-buf
    __shared__ float red[2][16][32];
    __shared__ float xnl[64];
    __shared__ float inv_s[64];
    __shared__ int   prod_cnt[16];
    __shared__ int   cons_cnt[16];

    const float* pn_arr = ws_f;
    const float* it_arr = ws_f + NPOS;

    const int tid  = threadIdx.x;
    const int lane = tid & 63;
    const int wave = tid >> 6;        // 0..15
    const int h    = lane >> 5;       // k-half within frag
    const int l31  = lane & 31;
    const int m0   = blockIdx.x * 64;

    if (tid < 16) { prod_cnt[tid] = 0; cons_cnt[tid] = 0; }

    // ---- stage x -> XBL8 (fp8 pair-packed) + xn partials (f32 exact) ----
    {
        float xp = 0.f;
        #pragma unroll
        for (int s = 0; s < 2; ++s) {
            const int row = wave * 2 + s;     // 0..31
            const int mhs = row >> 4;         // const per wave
            const int kgp = row & 15;
            const float* src = x + (size_t)(m0 + mhs * 32 + l31) * D
                               + kgp * 32 + h * 8;
            const float4 a = *(const float4*)src;
            const float4 c = *(const float4*)(src + 4);
            const float4 e = *(const float4*)(src + 16);
            const float4 g = *(const float4*)(src + 20);
            union { unsigned char bb[16]; uint4 u; } pk;
            pk.bb[0]=f2fp8(a.x);  pk.bb[1]=f2fp8(a.y);  pk.bb[2]=f2fp8(a.z);  pk.bb[3]=f2fp8(a.w);
            pk.bb[4]=f2fp8(c.x);  pk.bb[5]=f2fp8(c.y);  pk.bb[6]=f2fp8(c.z);  pk.bb[7]=f2fp8(c.w);
            pk.bb[8]=f2fp8(e.x);  pk.bb[9]=f2fp8(e.y);  pk.bb[10]=f2fp8(e.z); pk.bb[11]=f2fp8(e.w);
            pk.bb[12]=f2fp8(g.x); pk.bb[13]=f2fp8(g.y); pk.bb[14]=f2fp8(g.z); pk.bb[15]=f2fp8(g.w);
            *(uint4*)&XBL8[mhs][kgp][lane][0] = pk.u;
            xp += a.x*a.x + a.y*a.y + a.z*a.z + a.w*a.w
                + c.x*c.x + c.y*c.y + c.z*c.z + c.w*c.w
                + e.x*e.x + e.y*e.y + e.z*e.z + e.w*e.w
                + g.x*g.x + g.y*g.y + g.z*g.z + g.w*g.w;
        }
        xp += __shfl_xor(xp, 32, 64);
        if (lane < 32) red[wave >> 3][wave & 7][l31] = xp;
    }
    __syncthreads();
    if (tid < 64) {
        float s = 0.f;
        #pragma unroll
        for (int j = 0; j < 8; ++j) s += red[tid >> 5][j][tid & 31];
        xnl[tid] = s;
    }
    __syncthreads();

    const bool is_prod = (wave < 8);
    const int  pq = wave;        // producer n-slice
    const int  cq = wave - 8;    // consumer d-slice (64 wide)

    float xn0 = 0.f, xn1 = 0.f;
    if (is_prod) { xn0 = xnl[l31]; xn1 = xnl[32 + l31]; }

    f32x16_t a0 = (f32x16_t)0.f, a1 = (f32x16_t)0.f;
    f32x16_t a2 = (f32x16_t)0.f, a3 = (f32x16_t)0.f;
    float den0 = 0.f, den1 = 0.f;

    const u16* vt_b0 = vt3 + (size_t)(2 * cq)     * 256 * 512 + lane * 8;
    const u16* vt_b1 = vt3 + (size_t)(2 * cq + 1) * 256 * 512 + lane * 8;

    if (is_prod) {
        for (int t = 0; t < 16; ++t) {
            // ---- GEMM1 (fp8): S (32n x 64m), 16 b128 A-loads/tile ----
            a0 = (f32x16_t)0.f; a1 = (f32x16_t)0.f;
            const unsigned char* pbw = pb8
                + (size_t)(t * 8 + pq) * (16 * 1024) + lane * 16;
            #pragma unroll 4
            for (int kgp = 0; kgp < 16; ++kgp) {
                const long2_t A  = *(const long2_t*)(pbw + (size_t)kgp * 1024);
                const long2_t B0 = *(const long2_t*)&XBL8[0][kgp][lane][0];
                const long2_t B1 = *(const long2_t*)&XBL8[1][kgp][lane][0];
                a0 = __builtin_amdgcn_mfma_f32_32x32x16_fp8_fp8(A[0], B0[0], a0, 0, 0, 0);
                a1 = __builtin_amdgcn_mfma_f32_32x32x16_fp8_fp8(A[0], B1[0], a1, 0, 0, 0);
                a0 = __builtin_amdgcn_mfma_f32_32x32x16_fp8_fp8(A[1], B0[1], a0, 0, 0, 0);
                a1 = __builtin_amdgcn_mfma_f32_32x32x16_fp8_fp8(A[1], B1[1], a1, 0, 0, 0);
            }

            // credit: WTF[t%3] free once consumers finished tile t-3
            if (t >= 3) { lds_wait_ge(&cons_cnt[t - 3], 8); __threadfence_block(); }

            // ---- epilogue: w = 2^(dist*nit) -> WTF[t%3] (R10 exact) ----
            const int n0   = t * 256;
            const int bsel = t % 3;
            #pragma unroll
            for (int q = 0; q < 4; ++q) {
                const int nb = n0 + pq * 32 + 8 * q + 4 * h;
                const float4 pn4 = *(const float4*)(pn_arr + nb);
                const float4 it4 = *(const float4*)(it_arr + nb);
                const float pnv[4] = {pn4.x, pn4.y, pn4.z, pn4.w};
                const float itv[4] = {it4.x, it4.y, it4.z, it4.w};
                u16 h0[4], h1[4];
                #pragma unroll
                for (int r = 0; r < 4; ++r) {
                    const float d20 = xn0 + pnv[r] - 2.f * a0[4 * q + r];
                    const float w0  = exp2_hw(sqrtf(fmaxf(d20, 0.f)) * itv[r]);
                    h0[r] = f2bf(w0); den0 += bf2f(h0[r]);
                    const float d21 = xn1 + pnv[r] - 2.f * a1[4 * q + r];
                    const float w1  = exp2_hw(sqrtf(fmaxf(d21, 0.f)) * itv[r]);
                    h1[r] = f2bf(w1); den1 += bf2f(h1[r]);
                }
                const int kgp = pq * 2 + (q >> 1);
                const int gr  = (l31 + 32 * (q & 1)) * 8 + 4 * h;
                u16* dst0 = &WTF[bsel][0][kgp][gr];
                *(unsigned*)(dst0)     = (unsigned)h0[0] | ((unsigned)h0[1] << 16);
                *(unsigned*)(dst0 + 2) = (unsigned)h0[2] | ((unsigned)h0[3] << 16);
                u16* dst1 = &WTF[bsel][1][kgp][gr];
                *(unsigned*)(dst1)     = (unsigned)h1[0] | ((unsigned)h1[1] << 16);
                *(unsigned*)(dst1 + 2) = (unsigned)h1[2] | ((unsigned)h1[3] << 16);
            }
            __threadfence_block();                       // publish WTF writes
            if (lane == 0) atomicAdd(&prod_cnt[t], 1);   // signal
        }
    } else {
        for (int t = 0; t < 16; ++t) {
            const u16* vb0 = vt_b0 + (size_t)(t * 16) * 512;
            const u16* vb1 = vt_b1 + (size_t)(t * 16) * 512;
            // prefetch first 2 kg of V (flag-independent) before the spin
            short8_t P00 = *(const short8_t*)(vb0);
            short8_t P01 = *(const short8_t*)(vb1);
            short8_t P10 = *(const short8_t*)(vb0 + 512);
            short8_t P11 = *(const short8_t*)(vb1 + 512);

            lds_wait_ge(&prod_cnt[t], 8);                // tile t published
            __threadfence_block();                       // acquire
            const int bsel = t % 3;
            {   // kg = 0,1 with prefetched V
                const short8_t A0a = *(const short8_t*)&WTF[bsel][0][0][lane * 8];
                const short8_t A1a = *(const short8_t*)&WTF[bsel][1][0][lane * 8];
                a0 = __builtin_amdgcn_mfma_f32_32x32x16_bf16(A0a, P00, a0, 0, 0, 0);
                a1 = __builtin_amdgcn_mfma_f32_32x32x16_bf16(A0a, P01, a1, 0, 0, 0);
                a2 = __builtin_amdgcn_mfma_f32_32x32x16_bf16(A1a, P00, a2, 0, 0, 0);
                a3 = __builtin_amdgcn_mfma_f32_32x32x16_bf16(A1a, P01, a3, 0, 0, 0);
                const short8_t A0b = *(const short8_t*)&WTF[bsel][0][1][lane * 8];
                const short8_t A1b = *(const short8_t*)&WTF[bsel][1][1][lane * 8];
                a0 = __builtin_amdgcn_mfma_f32_32x32x16_bf16(A0b, P10, a0, 0, 0, 0);
                a1 = __builtin_amdgcn_mfma_f32_32x32x16_bf16(A0b, P11, a1, 0, 0, 0);
                a2 = __builtin_amdgcn_mfma_f32_32x32x16_bf16(A1b, P10, a2, 0, 0, 0);
                a3 = __builtin_amdgcn_mfma_f32_32x32x16_bf16(A1b, P11, a3, 0, 0, 0);
            }
            #pragma unroll 4
            for (int kg = 2; kg < 16; ++kg) {
                const short8_t A0 = *(const short8_t*)&WTF[bsel][0][kg][lane * 8];
                const short8_t A1 = *(const short8_t*)&WTF[bsel][1][kg][lane * 8];
                const short8_t B0 = *(const short8_t*)(vb0 + (size_t)kg * 512);
                const short8_t B1 = *(const short8_t*)(vb1 + (size_t)kg * 512);
                a0 = __builtin_amdgcn_mfma_f32_32x32x16_bf16(A0, B0, a0, 0, 0, 0);
                a1 = __builtin_amdgcn_mfma_f32_32x32x16_bf16(A0, B1, a1, 0, 0, 0);
                a2 = __builtin_amdgcn_mfma_f32_32x32x16_bf16(A1, B0, a2, 0, 0, 0);
                a3 = __builtin_amdgcn_mfma_f32_32x32x16_bf16(A1, B1, a3, 0, 0, 0);
            }
            __threadfence_block();                       // reads done
            if (lane == 0) atomicAdd(&cons_cnt[t], 1);   // release buffer
        }
    }
    __syncthreads();

    // ---------- den reduce + normalize + store ----------
    if (is_prod) {
        den0 += __shfl_xor(den0, 32, 64);
        den1 += __shfl_xor(den1, 32, 64);
        if (lane < 32) { red[0][pq][l31] = den0; red[1][pq][l31] = den1; }
    }
    __syncthreads();
    if (tid < 64) {
        float s = 0.f;
        #pragma unroll
        for (int j = 0; j < 8; ++j) s += red[tid >> 5][j][tid & 31];
        inv_s[tid] = 1.f / (s + 1e-8f);
    }
    __syncthreads();

    if (!is_prod) {
        #pragma unroll
        for (int q = 0; q < 4; ++q) {
            #pragma unroll
            for (int r = 0; r < 4; ++r) {
                const int mr = 8 * q + 4 * h + r;          // row within 32
                const float i0 = inv_s[mr];
                const float i1 = inv_s[32 + mr];
                float* o0 = out + (size_t)(m0 + mr) * D;
                float* o1 = out + (size_t)(m0 + 32 + mr) * D;
                o0[cq * 64 + l31]      = a0[4 * q + r] * i0;
                o0[cq * 64 + 32 + l31] = a1[4 * q + r] * i0;
                o1[cq * 64 + l31]      = a2[4 * q + r] * i1;
                o1[cq * 64 + 32 + l31] = a3[4 * q + r] * i1;
            }
        }
    }
}

extern "C" void kernel_launch(void* const* d_in, const int* in_sizes, int n_in,
                              void* d_out, int out_size, void* d_ws, size_t ws_size,
                              hipStream_t stream) {
    const float* xp  = (const float*)d_in[0];
    const float* pos = (const float*)d_in[1];
    const float* val = (const float*)d_in[2];
    const float* tmp = (const float*)d_in[3];
    const float* fsc = (const float*)d_in[4];
    const int*   frz = (const int*)d_in[5];
    float* outp = (float*)d_out;

    float*         ws_f = (float*)d_ws;
    unsigned char* pb8  = (unsigned char*)d_ws + 98304;
    u16*           vt3  = (u16*)((char*)d_ws + 4292608);

    pre_kernel<<<2048, 256, 0, stream>>>(xp, pos, val, tmp, fsc, frz,
                                         ws_f, pb8, vt3);
    tidal_main<<<M / 64, 1024, 0, stream>>>(ws_f, pb8, vt3, xp, outp);
}